// Round 1
// baseline (80.040 us; speedup 1.0000x reference)
//
#include <hip/hip_runtime.h>

// Problem constants (reference: B=2, S=H=D=96, DEPTH=8)
#define BB 2
#define SS 96
#define DD 96
#define BH (BB * SS)          // 192 (b,h) pairs
#define DSQ (DD * DD)         // 9216

// out[((b*96+h)*96+q)*96+v] = scale * K[b,h,udi,q] * r[v]
//   t[i] = sum_k Q[b,h,udi,k] * V[b,h,k,i]
//   r[v] = sum_i t[i] * DW[udi,i,v]
__global__ __launch_bounds__(256) void
mistral_mod_attn_kernel(const float* __restrict__ Q,
                        const float* __restrict__ K,
                        const float* __restrict__ V,
                        const float* __restrict__ DW,
                        const int* __restrict__ udi_p,
                        float* __restrict__ out) {
    const int bh  = blockIdx.x;        // 0..191  (= b*96 + h, h = original S index)
    const int tid = threadIdx.x;
    const int udi = *udi_p;

    __shared__ float q_lds[DD];
    __shared__ float t_lds[DD];
    __shared__ float r_lds[DD];
    __shared__ float kq_lds[DD];

    const long base = (long)bh * DSQ;                  // [b,h,0,0] offset (inputs & output)
    const float scale = 0.10206207261596575f;          // 1/sqrt(96) as f32

    // Load q-row and (pre-scaled) k-row for depth index udi
    if (tid < DD) {
        q_lds[tid]  = Q[base + (long)udi * DD + tid];
        kq_lds[tid] = K[base + (long)udi * DD + tid] * scale;
    }
    __syncthreads();

    // Phase 1: t[i] = sum_k q[k] * V[base + k*96 + i]   (coalesced across i)
    if (tid < DD) {
        float acc = 0.0f;
        const float* vp = V + base + tid;
        #pragma unroll 8
        for (int k = 0; k < DD; ++k) acc += q_lds[k] * vp[k * DD];
        t_lds[tid] = acc;
    }
    __syncthreads();

    // Phase 2: r[v] = sum_i t[i] * DW[udi*9216 + i*96 + v]   (coalesced across v)
    if (tid < DD) {
        float acc = 0.0f;
        const float* wp = DW + (long)udi * DSQ + tid;
        #pragma unroll 8
        for (int i = 0; i < DD; ++i) acc += t_lds[i] * wp[i * DD];
        r_lds[tid] = acc;
    }
    __syncthreads();

    // Phase 3: outer product: out[base + q*96 + v] = kq[q] * r[v]
    float* op = out + base;
    for (int idx = tid; idx < DSQ; idx += 256) {
        int q = idx / DD;
        int v = idx - q * DD;
        op[idx] = kq_lds[q] * r_lds[v];
    }
}

extern "C" void kernel_launch(void* const* d_in, const int* in_sizes, int n_in,
                              void* d_out, int out_size, void* d_ws, size_t ws_size,
                              hipStream_t stream) {
    const float* Q  = (const float*)d_in[0];
    const float* K  = (const float*)d_in[1];
    const float* V  = (const float*)d_in[2];
    const float* DW = (const float*)d_in[3];
    const int* udi  = (const int*)d_in[4];
    float* out = (float*)d_out;

    mistral_mod_attn_kernel<<<BH, 256, 0, stream>>>(Q, K, V, DW, udi, out);
}

// Round 3
// 76.184 us; speedup vs baseline: 1.0506x; 1.0506x over previous
//
#include <hip/hip_runtime.h>

// Problem constants (reference: B=2, S=H=D=96, DEPTH=8)
#define DD 96
#define BH 192                // (b,h) pairs = B*S
#define DSQ (DD * DD)         // 9216
#define NT 384                // 6 waves
#define KSPLIT 4
#define KCH (DD / KSPLIT)     // 24

// out[bh*9216 + q*96 + v] = scale * K[bh, udi, q] * r[v]
//   t[i] = sum_k Q[bh,udi,k] * V[bh,k,i]
//   r[v] = sum_i t[i] * DW[udi,i,v]
__global__ __launch_bounds__(NT) void
mistral_mod_attn_kernel(const float* __restrict__ Q,
                        const float* __restrict__ K,
                        const float* __restrict__ V,
                        const float* __restrict__ DW,
                        const int* __restrict__ udi_p,
                        float* __restrict__ out) {
    const int bh  = blockIdx.x;        // 0..191
    const int tid = threadIdx.x;
    const int udi = *udi_p;

    __shared__ float q_lds[DD];
    __shared__ float kq_lds[DD];
    __shared__ float part[KSPLIT][DD];
    __shared__ float t_lds[DD];
    __shared__ float r_lds[DD];

    const long base = (long)bh * DSQ;
    const float scale = 0.10206207261596575f;   // 1/sqrt(96)

    // Load q-row and pre-scaled k-row for depth index udi (coalesced)
    if (tid < DD) {
        q_lds[tid] = Q[base + (long)udi * DD + tid];
    } else if (tid < 2 * DD) {
        const int i = tid - DD;
        kq_lds[i] = K[base + (long)udi * DD + i] * scale;
    }
    __syncthreads();

    const int i = tid % DD;        // output index within row
    const int p = tid / DD;        // k-split group 0..3

    // Phase 1: t[i] = sum_k q[k] * V[base + k*96 + i], 4-way split over k.
    // All 24 loads per thread are independent -> single latency exposure.
    {
        float acc = 0.0f;
        const float* vp = V + base + (long)(p * KCH) * DD + i;
        #pragma unroll
        for (int k = 0; k < KCH; ++k) acc += q_lds[p * KCH + k] * vp[k * DD];
        part[p][i] = acc;
    }
    __syncthreads();
    if (tid < DD)
        t_lds[tid] = part[0][tid] + part[1][tid] + part[2][tid] + part[3][tid];
    __syncthreads();

    // Phase 2: r[v] = sum_i t[i] * DW[udi*9216 + i*96 + v], 4-way split over i.
    {
        float acc = 0.0f;
        const float* wp = DW + (long)udi * DSQ + (long)(p * KCH) * DD + i;
        #pragma unroll
        for (int k = 0; k < KCH; ++k) acc += t_lds[p * KCH + k] * wp[k * DD];
        part[p][i] = acc;
    }
    __syncthreads();
    if (tid < DD)
        r_lds[tid] = part[0][tid] + part[1][tid] + part[2][tid] + part[3][tid];
    __syncthreads();

    // Phase 3: outer product, vectorized float4 stores.
    // 9216 floats = 2304 float4; row = 24 float4.
    float4* op4 = (float4*)(out + base);
    for (int idx4 = tid; idx4 < DSQ / 4; idx4 += NT) {
        const int q  = idx4 / (DD / 4);
        const int v4 = idx4 - q * (DD / 4);
        const float kqv = kq_lds[q];
        const float4 rr = *(const float4*)&r_lds[v4 * 4];
        float4 o;
        o.x = kqv * rr.x; o.y = kqv * rr.y; o.z = kqv * rr.z; o.w = kqv * rr.w;
        op4[idx4] = o;
    }
}

extern "C" void kernel_launch(void* const* d_in, const int* in_sizes, int n_in,
                              void* d_out, int out_size, void* d_ws, size_t ws_size,
                              hipStream_t stream) {
    const float* Q  = (const float*)d_in[0];
    const float* K  = (const float*)d_in[1];
    const float* V  = (const float*)d_in[2];
    const float* DW = (const float*)d_in[3];
    const int* udi  = (const int*)d_in[4];
    float* out = (float*)d_out;

    mistral_mod_attn_kernel<<<BH, NT, 0, stream>>>(Q, K, V, DW, udi, out);
}

// Round 5
// 72.698 us; speedup vs baseline: 1.1010x; 1.0479x over previous
//
#include <hip/hip_runtime.h>

// Problem constants (reference: B=2, S=H=D=96, DEPTH=8)
#define DD 96
#define BH 192                // (b,h) pairs = B*S
#define DSQ (DD * DD)         // 9216
#define NT 384                // 6 waves
#define KSPLIT 4
#define KCH (DD / KSPLIT)     // 24

// out[bh*9216 + q*96 + v] = scale * K[bh,udi,q] * r[v]
//   t[i] = sum_k Q[bh,udi,k] * V[bh,k,i]
//   r[v] = sum_i t[i] * DW[udi,i,v]
//
// Latency shape: ALL global loads (V chunk, W chunk, q row, k row) are issued
// before any compute; one vmcnt drain instead of 3 serial round-trips.
__global__ __launch_bounds__(NT) void
mistral_mod_attn_kernel(const float* __restrict__ Q,
                        const float* __restrict__ K,
                        const float* __restrict__ V,
                        const float* __restrict__ DW,
                        const int* __restrict__ udi_p,
                        float* __restrict__ out) {
    const int bh  = blockIdx.x;        // 0..191
    const int tid = threadIdx.x;

    __shared__ float q_lds[DD];
    __shared__ float kq_lds[DD];
    __shared__ float part[KSPLIT][DD];
    __shared__ float t_lds[DD];
    __shared__ float r_lds[DD];

    const long base = (long)bh * DSQ;
    const float scale = 0.10206207261596575f;   // 1/sqrt(96)

    const int i = tid % DD;        // column index 0..95
    const int p = tid / DD;        // split group 0..3

    // --- Issue V loads first (no dependency on udi) ---
    float vreg[KCH];
    const float* vp = V + base + (long)(p * KCH) * DD + i;
    #pragma unroll
    for (int k = 0; k < KCH; ++k) vreg[k] = vp[k * DD];

    // --- udi (scalar load), then W / q / k loads ---
    const int udi = *udi_p;
    float wreg[KCH];
    const float* wp = DW + (long)udi * DSQ + (long)(p * KCH) * DD + i;
    #pragma unroll
    for (int k = 0; k < KCH; ++k) wreg[k] = wp[k * DD];

    if (tid < DD) {
        q_lds[tid] = Q[base + (long)udi * DD + tid];
    } else if (tid < 2 * DD) {
        const int c = tid - DD;
        kq_lds[c] = K[base + (long)udi * DD + c] * scale;
    }
    __syncthreads();   // q/k rows visible; vreg/wreg already in flight/landed

    // Phase 1: partial t over this thread's 24 rows (pure VALU)
    {
        float acc = 0.0f;
        #pragma unroll
        for (int k = 0; k < KCH; ++k) acc += q_lds[p * KCH + k] * vreg[k];
        part[p][i] = acc;
    }
    __syncthreads();
    if (tid < DD)
        t_lds[tid] = part[0][tid] + part[1][tid] + part[2][tid] + part[3][tid];
    __syncthreads();

    // Phase 2: partial r from registers (pure VALU)
    {
        float acc = 0.0f;
        #pragma unroll
        for (int k = 0; k < KCH; ++k) acc += t_lds[p * KCH + k] * wreg[k];
        part[p][i] = acc;
    }
    __syncthreads();
    if (tid < DD)
        r_lds[tid] = part[0][tid] + part[1][tid] + part[2][tid] + part[3][tid];
    __syncthreads();

    // Phase 3: outer product, float4 stores (2304 stores, 6 per thread)
    float4* op4 = (float4*)(out + base);
    #pragma unroll
    for (int idx4 = tid; idx4 < DSQ / 4; idx4 += NT) {
        const int q  = idx4 / (DD / 4);
        const int v4 = idx4 - q * (DD / 4);
        const float kqv = kq_lds[q];
        const float4 rr = *(const float4*)&r_lds[v4 * 4];
        float4 o;
        o.x = kqv * rr.x; o.y = kqv * rr.y; o.z = kqv * rr.z; o.w = kqv * rr.w;
        op4[idx4] = o;
    }
}

extern "C" void kernel_launch(void* const* d_in, const int* in_sizes, int n_in,
                              void* d_out, int out_size, void* d_ws, size_t ws_size,
                              hipStream_t stream) {
    const float* Q  = (const float*)d_in[0];
    const float* K  = (const float*)d_in[1];
    const float* V  = (const float*)d_in[2];
    const float* DW = (const float*)d_in[3];
    const int* udi  = (const int*)d_in[4];
    float* out = (float*)d_out;

    mistral_mod_attn_kernel<<<BH, NT, 0, stream>>>(Q, K, V, DW, udi, out);
}